// Round 1
// baseline (143.619 us; speedup 1.0000x reference)
//
#include <hip/hip_runtime.h>
#include <hip/hip_bf16.h>
#include <cstdint>

// Problem: B=64, D=1024, H=1024.
// Columns layout (6144 total): [0,1024) i_g | [1024,2048) f_g | [2048,3072) o_g
//                              [3072,4096) q | [4096,5120) k  | [5120,6144) v

#define BDIM 64
#define HDIM 1024
#define NCOL 6144

// ---------------- Kernel P: projections (partial-K GEMM) ----------------
// grid: (96 col-tiles, 8 K-chunks), 256 threads.
// Each block: 64 cols x 64 batch rows, K-chunk of 256.
// part layout: part[c][b][j]  (c in [0,8), b in [0,64), j in [0,6144))
__global__ __launch_bounds__(256) void proj_kernel(
    const float* __restrict__ input, const float* __restrict__ hvec,
    const float* __restrict__ w_ih, const float* __restrict__ w_hh,
    const float* __restrict__ wq, const float* __restrict__ wk,
    const float* __restrict__ wv, float* __restrict__ part)
{
    int ct = blockIdx.x;            // 0..95
    int c  = blockIdx.y;            // 0..7
    int jbase = ct * 64;            // global col base
    int o = jbase >> 10;            // 0..5 which output
    if (o >= 3 && c >= 4) return;   // q/k/v only have K=1024 (4 chunks)
    int jloc = jbase & 1023;

    const float* W; const float* src; int koff; int wrow;
    if (o < 3) {
        wrow = o * 1024 + jloc;
        if (c < 4) { W = w_ih; src = input; koff = c * 256; }
        else       { W = w_hh; src = hvec;  koff = (c - 4) * 256; }
    } else {
        wrow = jloc;
        W = (o == 3) ? wq : (o == 4) ? wk : wv;
        src = input; koff = c * 256;
    }

    __shared__ float Xs[32][68];   // transposed: [k][b], 68-pad keeps 16B align
    __shared__ float Ws[32][68];   // transposed: [k][j]

    int tid = threadIdx.x;
    int bg = tid >> 4;             // 0..15 -> rows bg*4..+3
    int jg = tid & 15;             // 0..15 -> cols jg*4..+3

    float acc[4][4] = {};

    for (int k0 = 0; k0 < 256; k0 += 32) {
        #pragma unroll
        for (int i = 0; i < 8; ++i) {
            int l = tid + i * 256;         // 0..2047
            int r = l >> 5;                // row 0..63
            int kk = l & 31;               // k 0..31
            Xs[kk][r] = src[(size_t)r * 1024 + koff + k0 + kk];
            Ws[kk][r] = W[(size_t)(wrow + r) * 1024 + koff + k0 + kk];
        }
        __syncthreads();
        #pragma unroll
        for (int kk = 0; kk < 32; ++kk) {
            float4 a = *(const float4*)&Xs[kk][bg * 4];
            float4 w4 = *(const float4*)&Ws[kk][jg * 4];
            acc[0][0] += a.x * w4.x; acc[0][1] += a.x * w4.y; acc[0][2] += a.x * w4.z; acc[0][3] += a.x * w4.w;
            acc[1][0] += a.y * w4.x; acc[1][1] += a.y * w4.y; acc[1][2] += a.y * w4.z; acc[1][3] += a.y * w4.w;
            acc[2][0] += a.z * w4.x; acc[2][1] += a.z * w4.y; acc[2][2] += a.z * w4.z; acc[2][3] += a.z * w4.w;
            acc[3][0] += a.w * w4.x; acc[3][1] += a.w * w4.y; acc[3][2] += a.w * w4.z; acc[3][3] += a.w * w4.w;
        }
        __syncthreads();
    }

    #pragma unroll
    for (int bi = 0; bi < 4; ++bi) {
        int b = bg * 4 + bi;
        float4 v4 = make_float4(acc[bi][0], acc[bi][1], acc[bi][2], acc[bi][3]);
        *(float4*)&part[((size_t)c * 64 + b) * NCOL + jbase + jg * 4] = v4;
    }
}

// ---------------- Kernel A: reduce chunks + bias + activation ----------------
__global__ __launch_bounds__(256) void act_kernel(
    const float* __restrict__ part, const float* __restrict__ bias,
    const float* __restrict__ wq_b, const float* __restrict__ wk_b,
    const float* __restrict__ wv_b, float* __restrict__ act)
{
    int idx = blockIdx.x * 256 + threadIdx.x;   // 0..64*6144
    int b = idx / NCOL, j = idx - b * NCOL;
    int nc = (j < 3072) ? 8 : 4;
    float s = 0.f;
    for (int cc = 0; cc < nc; ++cc)
        s += part[((size_t)cc * 64 + b) * NCOL + j];
    float bb;
    if (j < 3072) bb = bias[j];
    else if (j < 4096) bb = wq_b[j - 3072];
    else if (j < 5120) bb = wk_b[j - 4096];
    else bb = wv_b[j - 5120];
    s += bb;
    float r;
    if (j < 2048)      r = expf(s);                    // i_g, f_g
    else if (j < 3072) r = 1.f / (1.f + expf(-s));     // o_g
    else               r = s;                          // q, k, v
    act[idx] = r;
}

// ---------------- Kernel U: c_new = f*c + (i*v)*k, fused q-weighted row sums -
// grid: (32 row-tiles, 64 batches), 256 threads, each thread owns 4 cols (float4).
__global__ __launch_bounds__(256) void update_kernel(
    const float* __restrict__ c_in, const float* __restrict__ act,
    float* __restrict__ c_out, float* __restrict__ hpart)
{
    int t = blockIdx.x;            // 0..31
    int b = blockIdx.y;            // 0..63
    int tid = threadIdx.x;
    int col = tid * 4;
    const float* arow = act + (size_t)b * NCOL;
    float4 k4 = *(const float4*)&arow[4096 + col];
    float4 acc = make_float4(0.f, 0.f, 0.f, 0.f);
    size_t base = ((size_t)b * 1024 + (size_t)t * 32) * 1024;

    #pragma unroll 4
    for (int hh = 0; hh < 32; ++hh) {
        int hrow = t * 32 + hh;
        float f  = arow[1024 + hrow];
        float iv = arow[hrow] * arow[5120 + hrow];
        float qv = arow[3072 + hrow];
        float4 c4 = *(const float4*)&c_in[base + (size_t)hh * 1024 + col];
        float4 cn;
        cn.x = f * c4.x + iv * k4.x;
        cn.y = f * c4.y + iv * k4.y;
        cn.z = f * c4.z + iv * k4.z;
        cn.w = f * c4.w + iv * k4.w;
        *(float4*)&c_out[base + (size_t)hh * 1024 + col] = cn;
        acc.x += qv * cn.x;
        acc.y += qv * cn.y;
        acc.z += qv * cn.z;
        acc.w += qv * cn.w;
    }
    *(float4*)&hpart[((size_t)b * 32 + t) * 1024 + col] = acc;
}

// ---------------- Kernel R: h_new = o_g * sum_t hpart ----------------
__global__ __launch_bounds__(256) void readout_kernel(
    const float* __restrict__ hpart, const float* __restrict__ act,
    float* __restrict__ h_new)
{
    int idx = blockIdx.x * 256 + threadIdx.x;   // 0..65536
    int b = idx >> 10, j = idx & 1023;
    float s = 0.f;
    #pragma unroll
    for (int t = 0; t < 32; ++t)
        s += hpart[((size_t)b * 32 + t) * 1024 + j];
    h_new[idx] = act[(size_t)b * NCOL + 2048 + j] * s;
}

extern "C" void kernel_launch(void* const* d_in, const int* in_sizes, int n_in,
                              void* d_out, int out_size, void* d_ws, size_t ws_size,
                              hipStream_t stream)
{
    const float* input = (const float*)d_in[0];   // [64,1024]
    const float* hvec  = (const float*)d_in[1];   // [64,1024]
    const float* c_in  = (const float*)d_in[2];   // [64,1024,1024]
    const float* w_ih  = (const float*)d_in[3];   // [3072,1024]
    const float* w_hh  = (const float*)d_in[4];   // [3072,1024]
    const float* bias  = (const float*)d_in[5];   // [3072]
    const float* wq_w  = (const float*)d_in[6];   // [1024,1024]
    const float* wq_b  = (const float*)d_in[7];
    const float* wk_w  = (const float*)d_in[8];
    const float* wk_b  = (const float*)d_in[9];
    const float* wv_w  = (const float*)d_in[10];
    const float* wv_b  = (const float*)d_in[11];

    float* out   = (float*)d_out;
    float* h_new = out;                 // [64,1024]
    float* c_new = out + 64 * 1024;     // [64,1024,1024]

    // workspace layout (floats)
    float* ws    = (float*)d_ws;
    float* part  = ws;                              // 8*64*6144  = 3,145,728
    float* act   = part + (size_t)8 * 64 * NCOL;    // 64*6144    =   393,216
    float* hpart = act + (size_t)64 * NCOL;         // 64*32*1024 = 2,097,152

    proj_kernel<<<dim3(96, 8), 256, 0, stream>>>(input, hvec, w_ih, w_hh,
                                                 wq_w, wk_w, wv_w, part);
    act_kernel<<<(64 * NCOL) / 256, 256, 0, stream>>>(part, bias, wq_b, wk_b,
                                                      wv_b, act);
    update_kernel<<<dim3(32, 64), 256, 0, stream>>>(c_in, act, c_new, hpart);
    readout_kernel<<<(64 * 1024) / 256, 256, 0, stream>>>(hpart, act, h_new);
}

// Round 2
// 126.437 us; speedup vs baseline: 1.1359x; 1.1359x over previous
//
#include <hip/hip_runtime.h>
#include <hip/hip_bf16.h>
#include <cstdint>

// Problem: B=64, D=1024, H=1024.
// Columns layout (6144 total): [0,1024) i_g | [1024,2048) f_g | [2048,3072) o_g
//                              [3072,4096) q | [4096,5120) k  | [5120,6144) v

#define NCOL 6144

typedef __attribute__((ext_vector_type(8))) short short8;
typedef __attribute__((ext_vector_type(4))) float f32x4;
typedef __attribute__((ext_vector_type(4))) unsigned short u16x4;

static __device__ __forceinline__ unsigned short f2b(float f) {
    union { float f; uint32_t u; } v; v.f = f;
    uint32_t r = (v.u + 0x7FFFu + ((v.u >> 16) & 1u)) >> 16;  // RNE
    return (unsigned short)r;
}

// ---------------- Kernel P: projections via bf16 MFMA (partial-K GEMM) ------
// grid: (96 col-tiles, 8 K-chunks), 256 threads = 4 waves.
// Block: 64 cols x 64 batch rows, K-chunk 256. Wave w owns cols w*16..w*16+15.
// part layout: part[c][b][j]
__global__ __launch_bounds__(256) void proj_kernel(
    const float* __restrict__ input, const float* __restrict__ hvec,
    const float* __restrict__ w_ih, const float* __restrict__ w_hh,
    const float* __restrict__ wq, const float* __restrict__ wk,
    const float* __restrict__ wv, float* __restrict__ part)
{
    int ct = blockIdx.x;            // 0..95
    int c  = blockIdx.y;            // 0..7
    int jbase = ct * 64;
    int o = jbase >> 10;            // which output (0..5)
    if (o >= 3 && c >= 4) return;   // q/k/v have only K=1024 (4 chunks)
    int jloc = jbase & 1023;

    const float* W; const float* src; int koff; int wrow;
    if (o < 3) {
        wrow = o * 1024 + jloc;
        if (c < 4) { W = w_ih; src = input; koff = c * 256; }
        else       { W = w_hh; src = hvec;  koff = (c - 4) * 256; }
    } else {
        wrow = jloc;
        W = (o == 3) ? wq : (o == 4) ? wk : wv;
        src = input; koff = c * 256;
    }

    // bf16 tiles, row-major [row][K], +8 pad => row stride 528B (free 2-way banks)
    __shared__ unsigned short Als[64][264];   // X: 64 batches x 256 K
    __shared__ unsigned short Bls[64][264];   // W: 64 cols    x 256 K

    int tid = threadIdx.x;
    #pragma unroll
    for (int i = 0; i < 16; ++i) {          // stage A (X)
        int l = tid + i * 256;              // 0..4095 float4s
        int r = l >> 6;                     // row 0..63
        int k4 = (l & 63) << 2;             // k 0..252 step 4
        f32x4 x = *(const f32x4*)&src[(size_t)r * 1024 + koff + k4];
        u16x4 u; u[0] = f2b(x[0]); u[1] = f2b(x[1]); u[2] = f2b(x[2]); u[3] = f2b(x[3]);
        *(u16x4*)&Als[r][k4] = u;
    }
    #pragma unroll
    for (int i = 0; i < 16; ++i) {          // stage B (W)
        int l = tid + i * 256;
        int r = l >> 6;
        int k4 = (l & 63) << 2;
        f32x4 x = *(const f32x4*)&W[(size_t)(wrow + r) * 1024 + koff + k4];
        u16x4 u; u[0] = f2b(x[0]); u[1] = f2b(x[1]); u[2] = f2b(x[2]); u[3] = f2b(x[3]);
        *(u16x4*)&Bls[r][k4] = u;
    }
    __syncthreads();

    int lane = tid & 63;
    int w    = tid >> 6;                    // wave 0..3 -> col group
    int cn16 = lane & 15;                   // fragment col/row-select
    int kg   = lane >> 4;                   // 0..3 k-group

    f32x4 acc[4];
    #pragma unroll
    for (int m = 0; m < 4; ++m) { acc[m][0]=0.f; acc[m][1]=0.f; acc[m][2]=0.f; acc[m][3]=0.f; }

    #pragma unroll
    for (int ks = 0; ks < 8; ++ks) {
        int kb = ks * 32 + kg * 8;          // 16B-aligned
        short8 bf = *(const short8*)&Bls[w * 16 + cn16][kb];
        #pragma unroll
        for (int m = 0; m < 4; ++m) {
            short8 af = *(const short8*)&Als[m * 16 + cn16][kb];
            acc[m] = __builtin_amdgcn_mfma_f32_16x16x32_bf16(af, bf, acc[m], 0, 0, 0);
        }
    }

    // D layout: col = lane&15, row = (lane>>4)*4 + reg  (per m89)
    #pragma unroll
    for (int m = 0; m < 4; ++m) {
        #pragma unroll
        for (int r = 0; r < 4; ++r) {
            int b = m * 16 + kg * 4 + r;
            part[((size_t)c * 64 + b) * NCOL + jbase + w * 16 + cn16] = acc[m][r];
        }
    }
}

// ---------------- Kernel A: reduce chunks + bias + activation ----------------
__global__ __launch_bounds__(256) void act_kernel(
    const float* __restrict__ part, const float* __restrict__ bias,
    const float* __restrict__ wq_b, const float* __restrict__ wk_b,
    const float* __restrict__ wv_b, float* __restrict__ act)
{
    int idx = blockIdx.x * 256 + threadIdx.x;   // 0..64*6144
    int b = idx / NCOL, j = idx - b * NCOL;
    int nc = (j < 3072) ? 8 : 4;
    float s = 0.f;
    for (int cc = 0; cc < nc; ++cc)
        s += part[((size_t)cc * 64 + b) * NCOL + j];
    float bb;
    if (j < 3072) bb = bias[j];
    else if (j < 4096) bb = wq_b[j - 3072];
    else if (j < 5120) bb = wk_b[j - 4096];
    else bb = wv_b[j - 5120];
    s += bb;
    float r;
    if (j < 2048)      r = expf(s);                    // i_g, f_g
    else if (j < 3072) r = 1.f / (1.f + expf(-s));     // o_g
    else               r = s;                          // q, k, v
    act[idx] = r;
}

// ---------------- Kernel U: c_new = f*c + (i*v)*k, fused q-weighted row sums -
// grid: (32 row-tiles, 64 batches), 256 threads, each thread owns 4 cols.
// Nontemporal on the 537 MB zero-reuse c stream; gate scalars preloaded to LDS.
__global__ __launch_bounds__(256) void update_kernel(
    const float* __restrict__ c_in, const float* __restrict__ act,
    float* __restrict__ c_out, float* __restrict__ hpart)
{
    int t = blockIdx.x;            // 0..31
    int b = blockIdx.y;            // 0..63
    int tid = threadIdx.x;
    const float* arow = act + (size_t)b * NCOL;

    __shared__ float fs[32], ivs[32], qvs[32];
    if (tid < 32) {
        int hrow = t * 32 + tid;
        fs[tid]  = arow[1024 + hrow];
        ivs[tid] = arow[hrow] * arow[5120 + hrow];
        qvs[tid] = arow[3072 + hrow];
    }
    int col = tid * 4;
    f32x4 k4 = *(const f32x4*)&arow[4096 + col];
    __syncthreads();

    f32x4 acc; acc[0]=0.f; acc[1]=0.f; acc[2]=0.f; acc[3]=0.f;
    size_t base = ((size_t)b * 1024 + (size_t)t * 32) * 1024 + col;

    #pragma unroll 8
    for (int hh = 0; hh < 32; ++hh) {
        f32x4 c4 = __builtin_nontemporal_load((const f32x4*)(c_in + base + (size_t)hh * 1024));
        float f = fs[hh], iv = ivs[hh], qv = qvs[hh];
        f32x4 cn = f * c4 + iv * k4;
        __builtin_nontemporal_store(cn, (f32x4*)(c_out + base + (size_t)hh * 1024));
        acc += qv * cn;
    }
    *(f32x4*)&hpart[((size_t)b * 32 + t) * 1024 + col] = acc;
}

// ---------------- Kernel R: h_new = o_g * sum_t hpart ----------------
__global__ __launch_bounds__(256) void readout_kernel(
    const float* __restrict__ hpart, const float* __restrict__ act,
    float* __restrict__ h_new)
{
    int idx = blockIdx.x * 256 + threadIdx.x;   // 0..65536
    int b = idx >> 10, j = idx & 1023;
    float s = 0.f;
    #pragma unroll
    for (int t = 0; t < 32; ++t)
        s += hpart[((size_t)b * 32 + t) * 1024 + j];
    h_new[idx] = act[(size_t)b * NCOL + 2048 + j] * s;
}

extern "C" void kernel_launch(void* const* d_in, const int* in_sizes, int n_in,
                              void* d_out, int out_size, void* d_ws, size_t ws_size,
                              hipStream_t stream)
{
    (void)in_sizes; (void)n_in; (void)out_size; (void)ws_size;
    const float* input = (const float*)d_in[0];   // [64,1024]
    const float* hvec  = (const float*)d_in[1];   // [64,1024]
    const float* c_in  = (const float*)d_in[2];   // [64,1024,1024]
    const float* w_ih  = (const float*)d_in[3];   // [3072,1024]
    const float* w_hh  = (const float*)d_in[4];   // [3072,1024]
    const float* bias  = (const float*)d_in[5];   // [3072]
    const float* wq_w  = (const float*)d_in[6];   // [1024,1024]
    const float* wq_b  = (const float*)d_in[7];
    const float* wk_w  = (const float*)d_in[8];
    const float* wk_b  = (const float*)d_in[9];
    const float* wv_w  = (const float*)d_in[10];
    const float* wv_b  = (const float*)d_in[11];

    float* out   = (float*)d_out;
    float* h_new = out;                 // [64,1024]
    float* c_new = out + 64 * 1024;     // [64,1024,1024]

    float* ws    = (float*)d_ws;
    float* part  = ws;                              // 8*64*6144  = 3,145,728 f
    float* act   = part + (size_t)8 * 64 * NCOL;    // 64*6144
    float* hpart = act + (size_t)64 * NCOL;         // 64*32*1024

    proj_kernel<<<dim3(96, 8), 256, 0, stream>>>(input, hvec, w_ih, w_hh,
                                                 wq_w, wk_w, wv_w, part);
    act_kernel<<<(64 * NCOL) / 256, 256, 0, stream>>>(part, bias, wq_b, wk_b,
                                                      wv_b, act);
    update_kernel<<<dim3(32, 64), 256, 0, stream>>>(c_in, act, c_new, hpart);
    readout_kernel<<<(64 * 1024) / 256, 256, 0, stream>>>(hpart, act, h_new);
}